// Round 5
// baseline (484.942 us; speedup 1.0000x reference)
//
#include <hip/hip_runtime.h>
#include <hip/hip_bf16.h>
#include <math.h>

// ---------------- bucketed CSR build ----------------
// bucket = dst >> 8 (256 nodes/bucket). NB = ceil(N/256) <= 512.
// R12: (node,rel)-sorted csr -> run-length flushes. R18: also build
//  - eidpos[eid] = csr position (inverse map)
//  - srcb: src-bucketed records {srclocal|rel|csrpos} for k_msg
// so the aggregation becomes: random WRITES (k_msg) + sequential READS
// (k_att, k_fused2). R13-R17 showed random reads pin at ~16 outstanding
// lines/CU x ~640cy latency = ~58cyc/edge no matter the wave structure.

#define CSR_CHUNK 8192

__global__ void k_bhist(const int* __restrict__ dst, const int* __restrict__ src,
                        int* __restrict__ bcount, int* __restrict__ sbcount,
                        int E, int NB) {
    __shared__ int h[512];
    __shared__ int h2[512];
    int t = threadIdx.x;
    for (int i = t; i < NB; i += 256) { h[i] = 0; h2[i] = 0; }
    __syncthreads();
    int e0 = blockIdx.x * CSR_CHUNK;
    int e1 = min(e0 + CSR_CHUNK, E);
    for (int i = e0 + t; i < e1; i += 256) {
        atomicAdd(&h[dst[i] >> 8], 1);
        atomicAdd(&h2[src[i] >> 8], 1);
    }
    __syncthreads();
    for (int i = t; i < NB; i += 256) {
        int c = h[i];
        if (c) atomicAdd(&bcount[i], c);
        int c2 = h2[i];
        if (c2) atomicAdd(&sbcount[i], c2);
    }
}

// dual scan: dst buckets (bstart/gcur/rowptr[N]) and src buckets (sbstart/sgcur)
__global__ void k_bscan(const int* __restrict__ bcount, int* __restrict__ bstart,
                        int* __restrict__ gcur, int* __restrict__ rowptr,
                        const int* __restrict__ sbcount, int* __restrict__ sbstart,
                        int* __restrict__ sgcur, int NB, int N, int E) {
    __shared__ int s[512];
    int t = threadIdx.x;
    int v = (t < NB) ? bcount[t] : 0;
    s[t] = v;
    __syncthreads();
    for (int off = 1; off < 512; off <<= 1) {
        int a = (t >= off) ? s[t - off] : 0;
        __syncthreads();
        s[t] += a;
        __syncthreads();
    }
    int excl = s[t] - v;
    if (t < NB) { bstart[t] = excl; gcur[t] = excl; }
    if (t == 0) { bstart[NB] = E; rowptr[N] = E; }
    __syncthreads();
    int v2 = (t < NB) ? sbcount[t] : 0;
    s[t] = v2;
    __syncthreads();
    for (int off = 1; off < 512; off <<= 1) {
        int a = (t >= off) ? s[t - off] : 0;
        __syncthreads();
        s[t] += a;
        __syncthreads();
    }
    int excl2 = s[t] - v2;
    if (t < NB) { sbstart[t] = excl2; sgcur[t] = excl2; }
    if (t == 0) sbstart[NB] = E;
}

// pass A: scatter packed edges grouped by dst-bucket; also record eid.
// pack: dstlocal(8) << 20 | rel(3) << 17 | src(17)
__global__ void k_bscatter(const int* __restrict__ src, const int* __restrict__ dst,
                           const int* __restrict__ et, int* __restrict__ gcur,
                           unsigned* __restrict__ ebufA, int* __restrict__ ebufE,
                           int E, int NB) {
    __shared__ int h[512];
    __shared__ int basearr[512];
    int t = threadIdx.x;
    for (int i = t; i < NB; i += 256) h[i] = 0;
    __syncthreads();
    int e0 = blockIdx.x * CSR_CHUNK;
    int e1 = min(e0 + CSR_CHUNK, E);
    for (int i = e0 + t; i < e1; i += 256) atomicAdd(&h[dst[i] >> 8], 1);
    __syncthreads();
    for (int i = t; i < NB; i += 256) {
        int c = h[i];
        basearr[i] = c ? atomicAdd(&gcur[i], c) : 0;
        h[i] = 0;
    }
    __syncthreads();
    for (int i = e0 + t; i < e1; i += 256) {
        int d = dst[i];
        int b = d >> 8;
        int off = atomicAdd(&h[b], 1);
        int pos = basearr[b] + off;
        ebufA[pos] = ((unsigned)(d & 255) << 20) | ((unsigned)et[i] << 17) | (unsigned)src[i];
        ebufE[pos] = i;
    }
}

// pass B: per dst-bucket counting sort by (dstlocal,rel) -> rowptr, csr_pk
// (fallback), csr2 = dstlocal<<3|rel (ushort), eidpos[eid]=csrpos (if non-null)
__global__ void k_bsort(const unsigned* __restrict__ ebufA, const int* __restrict__ ebufE,
                        const int* __restrict__ bstart, int* __restrict__ rowptr,
                        int* __restrict__ csr_pk, unsigned short* __restrict__ csr2,
                        int* __restrict__ eidpos, int N) {
    __shared__ int lh[2048];
    __shared__ int ls[2048];
    __shared__ int ss[256];
    int b = blockIdx.x, t = threadIdx.x;
    int e0 = bstart[b], e1 = bstart[b + 1];
    for (int i = t; i < 2048; i += 256) lh[i] = 0;
    __syncthreads();
    for (int i = e0 + t; i < e1; i += 256) {
        unsigned u = ebufA[i];
        atomicAdd(&lh[(int)(((u >> 20) & 255) * 8 + ((u >> 17) & 7))], 1);
    }
    __syncthreads();
    int loc[8];
    int s = 0;
#pragma unroll
    for (int j = 0; j < 8; j++) {
        loc[j] = s;
        s += lh[t * 8 + j];
    }
    ss[t] = s;
    __syncthreads();
    for (int off = 1; off < 256; off <<= 1) {
        int a = (t >= off) ? ss[t - off] : 0;
        __syncthreads();
        ss[t] += a;
        __syncthreads();
    }
    int excl = ss[t] - s;
#pragma unroll
    for (int j = 0; j < 8; j++) ls[t * 8 + j] = excl + loc[j];
    int node = b * 256 + t;
    if (node < N) rowptr[node] = e0 + excl;
    __syncthreads();
    for (int i = t; i < 2048; i += 256) lh[i] = 0;
    __syncthreads();
    for (int i = e0 + t; i < e1; i += 256) {
        unsigned u = ebufA[i];
        int key = (int)(((u >> 20) & 255) * 8 + ((u >> 17) & 7));
        int off = atomicAdd(&lh[key], 1);
        int cpos = e0 + ls[key] + off;
        csr_pk[cpos] = (int)u;
        csr2[cpos] = (unsigned short)((((u >> 20) & 255) << 3) | ((u >> 17) & 7));
        if (eidpos) eidpos[ebufE[i]] = cpos;
    }
}

// pass C: src-bucketed records for k_msg: srclocal(8)<<24|rel(3)<<21|csrpos(21)
__global__ void k_bscatter2(const int* __restrict__ src, const int* __restrict__ et,
                            const int* __restrict__ eidpos, int* __restrict__ sgcur,
                            unsigned* __restrict__ srcb, int E, int NB) {
    __shared__ int h[512];
    __shared__ int basearr[512];
    int t = threadIdx.x;
    for (int i = t; i < NB; i += 256) h[i] = 0;
    __syncthreads();
    int e0 = blockIdx.x * CSR_CHUNK;
    int e1 = min(e0 + CSR_CHUNK, E);
    for (int i = e0 + t; i < e1; i += 256) atomicAdd(&h[src[i] >> 8], 1);
    __syncthreads();
    for (int i = t; i < NB; i += 256) {
        int c = h[i];
        basearr[i] = c ? atomicAdd(&sgcur[i], c) : 0;
        h[i] = 0;
    }
    __syncthreads();
    for (int i = e0 + t; i < e1; i += 256) {
        int sv = src[i];
        int b = sv >> 8;
        int off = atomicAdd(&h[b], 1);
        srcb[basearr[b] + off] = ((unsigned)(sv & 255) << 24) |
                                 ((unsigned)et[i] << 21) | (unsigned)eidpos[i];
    }
}

// ---------------- weight prep ----------------

__global__ void k_wt2(const float* __restrict__ W, __hip_bfloat16* __restrict__ hi,
                      __hip_bfloat16* __restrict__ lo, int OUT, int total) {
    int t = blockIdx.x * blockDim.x + threadIdx.x;
    if (t < total) {
        int per = 64 * OUT;
        int r = t / per;
        int rem = t % per;
        int i = rem / OUT;
        int o = rem % OUT;
        float v = W[t];
        __hip_bfloat16 h = __float2bfloat16(v);
        __hip_bfloat16 l = __float2bfloat16(v - __bfloat162float(h));
        size_t idx = (size_t)o * 512 + i * 8 + r;
        hi[idx] = h;
        lo[idx] = l;
    }
}

__global__ void k_wqk(const float* W, const float* Qv, const float* Kv,
                      float* wq, float* wk, int OUT) {
    int t = blockIdx.x * blockDim.x + threadIdx.x;
    if (t < 8 * 64) {
        int r = t >> 6, i = t & 63;
        const float* wrow = W + ((size_t)r * 64 + i) * OUT;
        float a = 0.f, b = 0.f;
        for (int o = 0; o < OUT; o++) {
            float w = wrow[o];
            a += w * Qv[o];
            b += w * Kv[o];
        }
        wq[t] = a;
        wk[t] = b;
    }
}

// ---------------- q/k projection + bf16 table emit ----------------
__global__ __launch_bounds__(256) void k_qk2(
        const float* __restrict__ xin, const float* __restrict__ wq,
        const float* __restrict__ wk, float* __restrict__ qn,
        float* __restrict__ kn, unsigned short* __restrict__ xbb, int N) {
    __shared__ float xt[64][65];
    __shared__ float swq[8 * 65], swk[8 * 65];
    int t = threadIdx.x;
    int nb0 = blockIdx.x * 64;
    for (int i = t; i < 512; i += 256) {
        int r = i >> 6, c = i & 63;
        swq[r * 65 + c] = wq[i];
        swk[r * 65 + c] = wk[i];
    }
    for (int i = t; i < 1024; i += 256) {
        int ns = i >> 4;
        int c4 = i & 15;
        int n = nb0 + ns;
        float4 v = {0.f, 0.f, 0.f, 0.f};
        if (n < N) v = ((const float4*)xin)[(size_t)n * 16 + c4];
        xt[ns][c4 * 4 + 0] = v.x;
        xt[ns][c4 * 4 + 1] = v.y;
        xt[ns][c4 * 4 + 2] = v.z;
        xt[ns][c4 * 4 + 3] = v.w;
        if (n < N) {
            __hip_bfloat16 b0 = __float2bfloat16(v.x);
            __hip_bfloat16 b1 = __float2bfloat16(v.y);
            __hip_bfloat16 b2 = __float2bfloat16(v.z);
            __hip_bfloat16 b3 = __float2bfloat16(v.w);
            ushort4 o;
            o.x = *(unsigned short*)&b0;
            o.y = *(unsigned short*)&b1;
            o.z = *(unsigned short*)&b2;
            o.w = *(unsigned short*)&b3;
            *(ushort4*)(xbb + (size_t)n * 64 + c4 * 4) = o;
        }
    }
    __syncthreads();
#pragma unroll
    for (int g = t; g < 512; g += 256) {
        int ns = g >> 3, r = g & 7;
        int n = nb0 + ns;
        if (n < N) {
            float qa = 0.f, ka = 0.f;
#pragma unroll
            for (int i = 0; i < 64; i++) {
                float xv = xt[ns][i];
                qa += xv * swq[r * 65 + i];
                ka += xv * swk[r * 65 + i];
            }
            qn[(size_t)n * 8 + r] = qa;
            kn[(size_t)n * 8 + r] = ka;
        }
    }
}

// ---------------- R18 message materialization ----------------
// k_msg: per src-bucket (x4 sub-blocks): stage the bucket's 256 xbb rows
// (32KB) + kn slice (8KB) in LDS; for each record write the 128B row to
// msg[csrpos] and kv[csrpos]. Random FULL-LINE stores: fire-and-forget,
// no MSHR stall. All reads LDS/sequential.
__global__ __launch_bounds__(256) void k_msg(
        const unsigned* __restrict__ srcb, const int* __restrict__ sbstart,
        const unsigned short* __restrict__ xbb, const float* __restrict__ kn,
        unsigned short* __restrict__ msg, float* __restrict__ kvarr, int N) {
    __shared__ unsigned short xrow[256 * 64];
    __shared__ float knl[256 * 8];
    int t = threadIdx.x;
    int wv = t >> 6;
    int lane = t & 63;
    int b = blockIdx.x >> 2;
    int qq = blockIdx.x & 3;
    int nb = b * 256;
    for (int idx = t; idx < 8192; idx += 256) {
        int node = nb + (idx >> 5);
        ((unsigned*)xrow)[idx] =
            (node < N) ? ((const unsigned*)xbb)[(size_t)node * 32 + (idx & 31)] : 0u;
    }
    for (int idx = t; idx < 2048; idx += 256) {
        int node = nb + (idx >> 3);
        knl[idx] = (node < N) ? kn[(size_t)node * 8 + (idx & 7)] : 0.f;
    }
    __syncthreads();
    int sb0 = sbstart[b], sb1 = sbstart[b + 1];
    int len = sb1 - sb0;
    int q0 = sb0 + ((len * qq) >> 2);
    int q1 = sb0 + ((len * (qq + 1)) >> 2);
    for (int i = q0 + wv; i < q1; i += 4) {
        unsigned rec = (unsigned)__builtin_amdgcn_readfirstlane((int)srcb[i]);
        int srcl = rec >> 24;
        int rel = (rec >> 21) & 7;
        int cp = rec & 0x1FFFFF;
        unsigned short xv = xrow[srcl * 64 + lane];
        msg[(size_t)cp * 64 + lane] = xv;
        if (lane == 0) kvarr[cp] = knl[srcl * 8 + rel];
    }
}

// k_att: per dst-bucket: edge-parallel tv = exp(leaky(q+kv)) from SEQUENTIAL
// kv + LDS-staged q; LDS denom -> invden[node]. Writes tva sequentially.
__global__ __launch_bounds__(256) void k_att(
        const unsigned short* __restrict__ csr2, const float* __restrict__ kvarr,
        const float* __restrict__ qn, const int* __restrict__ bstart,
        float* __restrict__ tva, float* __restrict__ invden, int N) {
    __shared__ float sq[2048];
    __shared__ float sden[256];
    int t = threadIdx.x;
    int b = blockIdx.x;
    int nb = b * 256;
    for (int idx = t; idx < 2048; idx += 256) {
        int node = nb + (idx >> 3);
        sq[idx] = (node < N) ? qn[(size_t)node * 8 + (idx & 7)] : 0.f;
    }
    sden[t] = 0.f;
    __syncthreads();
    int e0 = bstart[b], e1 = bstart[b + 1];
    for (int e = e0 + t; e < e1; e += 256) {
        int c2 = csr2[e];
        int dl = c2 >> 3;
        int rel = c2 & 7;
        float v = sq[dl * 8 + rel] + kvarr[e];
        v = fmaxf(v, 0.2f * v);
        float tvv = __expf(v);
        tva[e] = tvv;
        atomicAdd(&sden[dl], tvv);
    }
    __syncthreads();
    int node = nb + t;
    if (node < N) invden[node] = 1.f / (sden[t] + 1e-16f);
}

// ---------------- fused aggregation + transform ----------------
#define ZSTR 520

#define FLUSH8()                          \
    do {                                  \
        switch (currel) {                 \
            case 0: a0 += racc; break;    \
            case 1: a1 += racc; break;    \
            case 2: a2 += racc; break;    \
            case 3: a3 += racc; break;    \
            case 4: a4 += racc; break;    \
            case 5: a5 += racc; break;    \
            case 6: a6 += racc; break;    \
            case 7: a7 += racc; break;    \
        }                                 \
    } while (0)

// R18 drain: PURE SEQUENTIAL streams (msg rows, tva, csr2 in csr order).
// Per edge: 1 coalesced 128B row read + 1 fmac + SALU rel-run. Normalize by
// invden[node] at flush. No random reads anywhere.
template <int OUT, bool RELU>
__global__ __launch_bounds__(256) void k_fused2(
        const int* __restrict__ rowptr, const unsigned short* __restrict__ csr2,
        const float* __restrict__ tva, const float* __restrict__ invden,
        const unsigned short* __restrict__ msg,
        const __hip_bfloat16* __restrict__ wthi,
        const __hip_bfloat16* __restrict__ wtlo,
        const float* __restrict__ bias, float* __restrict__ xout, int N) {
    using v8s = __attribute__((ext_vector_type(8))) short;
    using v4f = __attribute__((ext_vector_type(4))) float;
    __shared__ unsigned short zt[16 * ZSTR];
    int t = threadIdx.x;
    int wvu = __builtin_amdgcn_readfirstlane(t >> 6);
    int lane = t & 63;
    int nb0 = blockIdx.x * 16;

    {
        uint4 zz = {0u, 0u, 0u, 0u};
#pragma unroll
        for (int q = 0; q < 4; q++)
            *(uint4*)&zt[(wvu * 4 + q) * ZSTR + lane * 8] = zz;
    }

#pragma unroll 1
    for (int q = 0; q < 4; q++) {
        int wid = nb0 + wvu * 4 + q;
        if (wid >= N) break;
        int r0 = rowptr[wid];
        int r1 = rowptr[wid + 1];
        float a0 = 0.f, a1 = 0.f, a2 = 0.f, a3 = 0.f;
        float a4 = 0.f, a5 = 0.f, a6 = 0.f, a7 = 0.f;
        float racc = 0.f;
        int currel = 0;
#pragma unroll 1
        for (int j = r0; j < r1; j += 16) {
            int c2[16];
            float tvv[16];
            unsigned short xu[16];
#pragma unroll
            for (int u = 0; u < 16; u++) {
                int ii = (j + u < r1) ? (j + u) : (r1 - 1);
                c2[u] = csr2[ii];
                tvv[u] = (j + u < r1) ? tva[ii] : 0.f;
            }
#pragma unroll
            for (int u = 0; u < 16; u++) {
                int ii = (j + u < r1) ? (j + u) : (r1 - 1);
                xu[u] = msg[(size_t)ii * 64 + lane];
            }
#pragma unroll
            for (int u = 0; u < 16; u++) {
                int rl = c2[u] & 7;
                if (rl != currel) {
                    FLUSH8();
                    currel = rl;
                    racc = 0.f;
                }
                racc += tvv[u] * __uint_as_float(((unsigned)xu[u]) << 16);
            }
        }
        FLUSH8();
        float inv = invden[wid];
        float av[8] = {a0, a1, a2, a3, a4, a5, a6, a7};
        unsigned short us[8];
#pragma unroll
        for (int r = 0; r < 8; r++) {
            __hip_bfloat16 b = __float2bfloat16(av[r] * inv);
            us[r] = *(unsigned short*)&b;
        }
        uint4 pack;
        pack.x = (unsigned)us[0] | ((unsigned)us[1] << 16);
        pack.y = (unsigned)us[2] | ((unsigned)us[3] << 16);
        pack.z = (unsigned)us[4] | ((unsigned)us[5] << 16);
        pack.w = (unsigned)us[6] | ((unsigned)us[7] << 16);
        *(uint4*)&zt[(wvu * 4 + q) * ZSTR + lane * 8] = pack;
    }
    __syncthreads();

    int quad = lane >> 4;
    int l15 = lane & 15;
    int nt = wvu;
    if (nt * 16 < OUT) {
        const short* wh = (const short*)wthi;
        const short* wl = (const short*)wtlo;
        v4f acc = {0.f, 0.f, 0.f, 0.f};
#pragma unroll
        for (int k0 = 0; k0 < 512; k0 += 32) {
            int koff = k0 + quad * 8;
            v8s A = *(const v8s*)&zt[l15 * ZSTR + koff];
            v8s bh = *(const v8s*)(wh + (size_t)(nt * 16 + l15) * 512 + koff);
            v8s bl = *(const v8s*)(wl + (size_t)(nt * 16 + l15) * 512 + koff);
            acc = __builtin_amdgcn_mfma_f32_16x16x32_bf16(A, bh, acc, 0, 0, 0);
            acc = __builtin_amdgcn_mfma_f32_16x16x32_bf16(A, bl, acc, 0, 0, 0);
        }
        float bcol = bias[nt * 16 + l15];
#pragma unroll
        for (int g = 0; g < 4; g++) {
            int row = nb0 + quad * 4 + g;
            if (row < N) {
                float o = acc[g] + bcol;
                if (RELU) o = fmaxf(o, 0.f);
                xout[(size_t)row * OUT + nt * 16 + l15] = o;
            }
        }
    }
}

// ---------------- R17 fallback (random-gather drain) ----------------
template <int OUT, bool RELU>
__global__ __launch_bounds__(256) void k_fused(
        const int* __restrict__ rowptr, const int* __restrict__ csr,
        const float* __restrict__ qn, const float* __restrict__ kn,
        const unsigned short* __restrict__ xb,
        const __hip_bfloat16* __restrict__ wthi,
        const __hip_bfloat16* __restrict__ wtlo,
        const float* __restrict__ bias, float* __restrict__ xout, int N) {
    using v8s = __attribute__((ext_vector_type(8))) short;
    using v4f = __attribute__((ext_vector_type(4))) float;
    __shared__ unsigned short zt[16 * ZSTR];
    int t = threadIdx.x;
    int wvu = __builtin_amdgcn_readfirstlane(t >> 6);
    int lane = t & 63;
    int nb0 = blockIdx.x * 16;
    {
        uint4 zz = {0u, 0u, 0u, 0u};
#pragma unroll
        for (int q = 0; q < 4; q++)
            *(uint4*)&zt[(wvu * 4 + q) * ZSTR + lane * 8] = zz;
    }
#pragma unroll 1
    for (int q = 0; q < 4; q++) {
        int wid = nb0 + wvu * 4 + q;
        if (wid >= N) break;
        int r0 = rowptr[wid];
        int r1 = rowptr[wid + 1];
        int qvec = 0;
        if (lane < 8) qvec = ((const int*)qn)[wid * 8 + lane];
        float a0 = 0.f, a1 = 0.f, a2 = 0.f, a3 = 0.f;
        float a4 = 0.f, a5 = 0.f, a6 = 0.f, a7 = 0.f;
        float racc = 0.f, denom = 0.f;
        int currel = 0;
#pragma unroll 1
        for (int j = r0; j < r1; j += 16) {
            int pk[16];
            float kv[16];
            unsigned short xu[16];
#pragma unroll
            for (int u = 0; u < 16; u++) {
                int ii = (j + u < r1) ? (j + u) : (r1 - 1);
                pk[u] = csr[ii];
            }
#pragma unroll
            for (int u = 0; u < 16; u++) {
                int s_ = pk[u] & 0x1FFFF;
                int r_ = (pk[u] >> 17) & 7;
                kv[u] = kn[(size_t)s_ * 8 + r_];
            }
#pragma unroll
            for (int u = 0; u < 16; u++)
                xu[u] = xb[(size_t)(pk[u] & 0x1FFFF) * 64 + lane];
#pragma unroll
            for (int u = 0; u < 16; u++) {
                int rl = (pk[u] >> 17) & 7;
                float qv = __uint_as_float(__builtin_amdgcn_readlane(qvec, rl));
                float v = qv + kv[u];
                v = fmaxf(v, 0.2f * v);
                float tv = __expf(v);
                if (j + u >= r1) tv = 0.f;
                if (rl != currel) {
                    FLUSH8();
                    currel = rl;
                    racc = 0.f;
                }
                racc += tv * __uint_as_float(((unsigned)xu[u]) << 16);
                denom += tv;
            }
        }
        FLUSH8();
        float inv = 1.f / (denom + 1e-16f);
        float av[8] = {a0, a1, a2, a3, a4, a5, a6, a7};
        unsigned short us[8];
#pragma unroll
        for (int r = 0; r < 8; r++) {
            __hip_bfloat16 b = __float2bfloat16(av[r] * inv);
            us[r] = *(unsigned short*)&b;
        }
        uint4 pack;
        pack.x = (unsigned)us[0] | ((unsigned)us[1] << 16);
        pack.y = (unsigned)us[2] | ((unsigned)us[3] << 16);
        pack.z = (unsigned)us[4] | ((unsigned)us[5] << 16);
        pack.w = (unsigned)us[6] | ((unsigned)us[7] << 16);
        *(uint4*)&zt[(wvu * 4 + q) * ZSTR + lane * 8] = pack;
    }
    __syncthreads();
    int quad = lane >> 4;
    int l15 = lane & 15;
    int nt = wvu;
    if (nt * 16 < OUT) {
        const short* wh = (const short*)wthi;
        const short* wl = (const short*)wtlo;
        v4f acc = {0.f, 0.f, 0.f, 0.f};
#pragma unroll
        for (int k0 = 0; k0 < 512; k0 += 32) {
            int koff = k0 + quad * 8;
            v8s A = *(const v8s*)&zt[l15 * ZSTR + koff];
            v8s bh = *(const v8s*)(wh + (size_t)(nt * 16 + l15) * 512 + koff);
            v8s bl = *(const v8s*)(wl + (size_t)(nt * 16 + l15) * 512 + koff);
            acc = __builtin_amdgcn_mfma_f32_16x16x32_bf16(A, bh, acc, 0, 0, 0);
            acc = __builtin_amdgcn_mfma_f32_16x16x32_bf16(A, bl, acc, 0, 0, 0);
        }
        float bcol = bias[nt * 16 + l15];
#pragma unroll
        for (int g = 0; g < 4; g++) {
            int row = nb0 + quad * 4 + g;
            if (row < N) {
                float o = acc[g] + bcol;
                if (RELU) o = fmaxf(o, 0.f);
                xout[(size_t)row * OUT + nt * 16 + l15] = o;
            }
        }
    }
}

// ---------------- host launch ----------------

extern "C" void kernel_launch(void* const* d_in, const int* in_sizes, int n_in,
                              void* d_out, int out_size, void* d_ws, size_t ws_size,
                              hipStream_t stream) {
    const float* x   = (const float*)d_in[0];
    const int*   ei  = (const int*)d_in[1];
    const int*   et  = (const int*)d_in[2];
    const float* W0  = (const float*)d_in[3];
    const float* Q0  = (const float*)d_in[4];
    const float* K0  = (const float*)d_in[5];
    const float* b0  = (const float*)d_in[6];
    const float* W1  = (const float*)d_in[7];
    const float* Q1  = (const float*)d_in[8];
    const float* K1  = (const float*)d_in[9];
    const float* b1  = (const float*)d_in[10];
    float* out = (float*)d_out;

    const int N = in_sizes[0] / 64;
    const int E = in_sizes[2];
    const int* src = ei;
    const int* dst = ei + E;
    const int NB = (N + 255) >> 8;  // <= 512

    char* p = (char*)d_ws;
    auto alloc = [&](size_t bytes) -> void* {
        void* r = (void*)p;
        p += ((bytes + 255) / 256) * 256;
        return r;
    };
    // core (fallback-sufficient) allocations
    int* rowptr   = (int*)alloc((size_t)(N + 1) * 4);
    int* bcount   = (int*)alloc(513 * 4);   // contiguous zero-region start
    int* gcur     = (int*)alloc(513 * 4);
    int* sbcount  = (int*)alloc(513 * 4);
    int* sgcur    = (int*)alloc(513 * 4);
    int* bstart   = (int*)alloc(513 * 4);
    int* sbstart  = (int*)alloc(513 * 4);
    unsigned* ebufA = (unsigned*)alloc((size_t)E * 4);
    int* ebufE    = (int*)alloc((size_t)E * 4);
    int* csr_pk   = (int*)alloc((size_t)E * 4);
    unsigned short* csr2 = (unsigned short*)alloc((size_t)E * 2);
    float* wq     = (float*)alloc(8 * 64 * 4);
    float* wk     = (float*)alloc(8 * 64 * 4);
    float* qn     = (float*)alloc((size_t)N * 8 * 4);
    float* kn     = (float*)alloc((size_t)N * 8 * 4);
    __hip_bfloat16* wthi = (__hip_bfloat16*)alloc((size_t)64 * 512 * 2);
    __hip_bfloat16* wtlo = (__hip_bfloat16*)alloc((size_t)64 * 512 * 2);
    float* h      = (float*)alloc((size_t)N * 64 * 4);
    unsigned short* xbb = (unsigned short*)alloc((size_t)N * 64 * 2);
    // new-path extras
    int* eidpos   = (int*)alloc((size_t)E * 4);
    unsigned* srcb = (unsigned*)alloc((size_t)E * 4);
    float* tva    = (float*)alloc((size_t)E * 4);
    float* kvarr  = (float*)alloc((size_t)E * 4);
    float* invden = (float*)alloc((size_t)N * 4);
    unsigned short* msg = (unsigned short*)alloc((size_t)E * 64 * 2);  // 128B/edge

    size_t need = (size_t)(p - (char*)d_ws);
    bool newok = (need <= ws_size) && (E < (1 << 21)) && (NB <= 512);

    // --- CSR build ---
    int nchunks = (E + CSR_CHUNK - 1) / CSR_CHUNK;
    hipMemsetAsync(bcount, 0, 4 * 2304, stream);  // bcount,gcur,sbcount,sgcur (padded)
    k_bhist<<<nchunks, 256, 0, stream>>>(dst, src, bcount, sbcount, E, NB);
    k_bscan<<<1, 512, 0, stream>>>(bcount, bstart, gcur, rowptr,
                                   sbcount, sbstart, sgcur, NB, N, E);
    k_bscatter<<<nchunks, 256, 0, stream>>>(src, dst, et, gcur, ebufA, ebufE, E, NB);
    k_bsort<<<NB, 256, 0, stream>>>(ebufA, ebufE, bstart, rowptr, csr_pk, csr2,
                                    newok ? eidpos : (int*)nullptr, N);
    if (newok)
        k_bscatter2<<<nchunks, 256, 0, stream>>>(src, et, eidpos, sgcur, srcb, E, NB);

    int nfb = (N + 15) / 16;
    int nqkb = (N + 63) / 64;

    // --- layer 0: 64 -> 64, relu ---
    k_wqk<<<2, 256, 0, stream>>>(W0, Q0, K0, wq, wk, 64);
    k_qk2<<<nqkb, 256, 0, stream>>>(x, wq, wk, qn, kn, xbb, N);
    k_wt2<<<(8 * 64 * 64 + 255) / 256, 256, 0, stream>>>(W0, wthi, wtlo, 64, 8 * 64 * 64);
    if (newok) {
        k_msg<<<NB * 4, 256, 0, stream>>>(srcb, sbstart, xbb, kn, msg, kvarr, N);
        k_att<<<NB, 256, 0, stream>>>(csr2, kvarr, qn, bstart, tva, invden, N);
        k_fused2<64, true><<<nfb, 256, 0, stream>>>(rowptr, csr2, tva, invden, msg,
                                                    wthi, wtlo, b0, h, N);
    } else {
        k_fused<64, true><<<nfb, 256, 0, stream>>>(rowptr, csr_pk, qn, kn, xbb,
                                                   wthi, wtlo, b0, h, N);
    }

    // --- layer 1: 64 -> 32, no relu ---
    k_wqk<<<2, 256, 0, stream>>>(W1, Q1, K1, wq, wk, 32);
    k_qk2<<<nqkb, 256, 0, stream>>>(h, wq, wk, qn, kn, xbb, N);
    k_wt2<<<(8 * 64 * 32 + 255) / 256, 256, 0, stream>>>(W1, wthi, wtlo, 32, 8 * 64 * 32);
    if (newok) {
        k_msg<<<NB * 4, 256, 0, stream>>>(srcb, sbstart, xbb, kn, msg, kvarr, N);
        k_att<<<NB, 256, 0, stream>>>(csr2, kvarr, qn, bstart, tva, invden, N);
        k_fused2<32, false><<<nfb, 256, 0, stream>>>(rowptr, csr2, tva, invden, msg,
                                                     wthi, wtlo, b1, out, N);
    } else {
        k_fused<32, false><<<nfb, 256, 0, stream>>>(rowptr, csr_pk, qn, kn, xbb,
                                                    wthi, wtlo, b1, out, N);
    }
}